// Round 2
// baseline (3056.746 us; speedup 1.0000x reference)
//
#include <hip/hip_runtime.h>
#include <hip/hip_bf16.h>

// ---------------- problem constants ----------------
namespace {
constexpr int N_ = 2048, C_ = 128, I_ = 9, E_ = 10;
constexpr int K3_ = 23, K2_ = 8, K1_ = 3;
constexpr int J3_ = 729, J2_ = 81, J1_ = 9;   // I^3, I^2, I
constexpr int M_ = 4;                          // nodes per contraction block
constexpr int CHUNKS_ = (N_ + M_ - 1) / M_;    // 512

// workspace layout (units: 4-byte words); total ~21 MB — assumes ws_size >= 21MB
constexpr int O_ELEM  = 0;            // int[N]
constexpr int O_ORDER = N_;           // int[N]  nodes sorted by element
constexpr int O_BOFF  = 2 * N_;       // int[E+1] bucket offsets
constexpr int O_V3_0  = O_BOFF + 16;
constexpr int S_V3_0  = E_ * 1 * J3_ * C_;     // 933120
constexpr int O_V3_1  = O_V3_0 + S_V3_0;
constexpr int S_V3_1  = E_ * 3 * J3_ * C_;     // 2799360
constexpr int O_V2_0  = O_V3_1 + S_V3_1;
constexpr int S_V2_0  = E_ * 1 * J2_ * C_;
constexpr int O_V2_1  = O_V2_0 + S_V2_0;
constexpr int S_V2_1  = E_ * 3 * J2_ * C_;
constexpr int O_V1_0  = O_V2_1 + S_V2_1;
constexpr int S_V1_0  = E_ * 1 * J1_ * C_;
constexpr int O_V1_1  = O_V1_0 + S_V1_0;
constexpr int S_V1_1  = E_ * 3 * J1_ * C_;
constexpr int O_F     = O_V1_1 + S_V1_1;       // float[N][4][C]
constexpr int VPRE_TOTAL = S_V3_0 + S_V3_1 + S_V2_0 + S_V2_1 + S_V1_0 + S_V1_1; // 4193280
}

// ---------------- kernel 1: bucket nodes by element (node_attrs is one-hot) --
__global__ void bucket_kernel(const float* __restrict__ attrs,
                              int* __restrict__ elem,
                              int* __restrict__ order,
                              int* __restrict__ boff) {
  __shared__ int cnt[E_], base_s[E_ + 1], cur[E_];
  int tid = threadIdx.x;
  if (tid < E_) cnt[tid] = 0;
  __syncthreads();
  for (int n = tid; n < N_; n += blockDim.x) {
    const float* a = attrs + n * E_;
    int best = 0; float bv = a[0];
    for (int e = 1; e < E_; ++e) { float v = a[e]; if (v > bv) { bv = v; best = e; } }
    elem[n] = best;
    atomicAdd(&cnt[best], 1);
  }
  __syncthreads();
  if (tid == 0) {
    int s = 0;
    for (int e = 0; e < E_; ++e) { base_s[e] = s; cur[e] = s; s += cnt[e]; }
    base_s[E_] = s;
  }
  __syncthreads();
  for (int n = tid; n < N_; n += blockDim.x) {
    int p = atomicAdd(&cur[elem[n]], 1);
    order[p] = n;
  }
  if (tid <= E_) boff[tid] = base_s[tid];
}

// ---------------- kernel 2: V[e,d,j,c] = sum_k U[d,j,k] * W[e,k,c] ----------
__device__ __forceinline__ void vpre_one(const float* __restrict__ U,
                                         const float* __restrict__ W,
                                         float* __restrict__ V,
                                         int D, int J, int K, int idx) {
  int c = idx % C_;
  int r = idx / C_;
  int j = r % J; r /= J;
  int d = r % D;
  int e = r / D;
  const float* Urow = U + (d * J + j) * K;
  const float* Wcol = W + e * K * C_ + c;
  float acc = 0.f;
  for (int k = 0; k < K; ++k) acc = fmaf(Urow[k], Wcol[k * C_], acc);
  V[idx] = acc;
}

__global__ void vpre_kernel(const float* __restrict__ U3_0, const float* __restrict__ W3_0,
                            const float* __restrict__ U2_0, const float* __restrict__ W2_0,
                            const float* __restrict__ U1_0, const float* __restrict__ W1_0,
                            const float* __restrict__ U3_1, const float* __restrict__ W3_1,
                            const float* __restrict__ U2_1, const float* __restrict__ W2_1,
                            const float* __restrict__ U1_1, const float* __restrict__ W1_1,
                            float* __restrict__ ws_f) {
  int idx = blockIdx.x * blockDim.x + threadIdx.x;
  if (idx < S_V3_0) { vpre_one(U3_0, W3_0, ws_f + O_V3_0, 1, J3_, K3_, idx); return; }
  idx -= S_V3_0;
  if (idx < S_V3_1) { vpre_one(U3_1, W3_1, ws_f + O_V3_1, 3, J3_, K3_, idx); return; }
  idx -= S_V3_1;
  if (idx < S_V2_0) { vpre_one(U2_0, W2_0, ws_f + O_V2_0, 1, J2_, K2_, idx); return; }
  idx -= S_V2_0;
  if (idx < S_V2_1) { vpre_one(U2_1, W2_1, ws_f + O_V2_1, 3, J2_, K2_, idx); return; }
  idx -= S_V2_1;
  if (idx < S_V1_0) { vpre_one(U1_0, W1_0, ws_f + O_V1_0, 1, J1_, K1_, idx); return; }
  idx -= S_V1_0;
  if (idx < S_V1_1) { vpre_one(U1_1, W1_1, ws_f + O_V1_1, 3, J1_, K1_, idx); }
}

// ---------------- kernel 3: symmetric contraction per (node, channel) -------
// f[d] = sum_p x_p * ( V1[d,p] + sum_q x_q * ( V2[d,pq] + sum_i x_i * V3[d,pq,i] ) )
// block: 64 threads (half of C); grid: (chunk, e, csel*4+dsel); M_ same-element
// nodes per block so each V3 load feeds M_ FMAs.
__global__ __launch_bounds__(64) void contract_kernel(
    const float* __restrict__ x, const float* __restrict__ ws_f,
    const int* __restrict__ order, const int* __restrict__ boff,
    float* __restrict__ fbuf) {
  int e = blockIdx.y;
  int z = blockIdx.z;
  int csel = z >> 2, dsel = z & 3;
  int b0 = boff[e];
  int cnt_e = boff[e + 1] - b0;
  int base = blockIdx.x * M_;
  if (base >= cnt_e) return;
  int cnt = cnt_e - base; if (cnt > M_) cnt = M_;
  int c = threadIdx.x + (csel << 6);

  int nn[M_];
  #pragma unroll
  for (int m = 0; m < M_; ++m) nn[m] = order[b0 + base + (m < cnt ? m : cnt - 1)];

  float xm[M_][I_];
  #pragma unroll
  for (int m = 0; m < M_; ++m) {
    const float* xp = x + (nn[m] * C_ + c) * I_;
    #pragma unroll
    for (int i = 0; i < I_; ++i) xm[m][i] = xp[i];
  }

  const float* V3; const float* V2; const float* V1;
  if (dsel == 0) {
    V3 = ws_f + O_V3_0 + e * J3_ * C_;
    V2 = ws_f + O_V2_0 + e * J2_ * C_;
    V1 = ws_f + O_V1_0 + e * J1_ * C_;
  } else {
    int d = dsel - 1;
    V3 = ws_f + O_V3_1 + (e * 3 + d) * J3_ * C_;
    V2 = ws_f + O_V2_1 + (e * 3 + d) * J2_ * C_;
    V1 = ws_f + O_V1_1 + (e * 3 + d) * J1_ * C_;
  }

  float f[M_] = {};
  for (int p = 0; p < I_; ++p) {
    float ap[M_] = {};
    #pragma unroll
    for (int q = 0; q < I_; ++q) {
      int pq = p * I_ + q;
      float v2 = V2[pq * C_ + c];
      float t[M_];
      #pragma unroll
      for (int m = 0; m < M_; ++m) t[m] = v2;
      const float* v3p = V3 + pq * I_ * C_ + c;
      #pragma unroll
      for (int i = 0; i < I_; ++i) {
        float v = v3p[i * C_];
        #pragma unroll
        for (int m = 0; m < M_; ++m) t[m] = fmaf(xm[m][i], v, t[m]);
      }
      #pragma unroll
      for (int m = 0; m < M_; ++m) ap[m] = fmaf(t[m], xm[m][q], ap[m]);
    }
    float v1 = V1[p * C_ + c];
    #pragma unroll
    for (int m = 0; m < M_; ++m) f[m] = fmaf(ap[m] + v1, xm[m][p], f[m]);
  }

  #pragma unroll
  for (int m = 0; m < M_; ++m)
    if (m < cnt) fbuf[(nn[m] * 4 + dsel) * C_ + c] = f[m];
}

// ---------------- kernel 4: equivariant linear + skip ------------------------
// y0[n,w] = inv * sum_u f[n,0,u] Wlin0[u,w];  y1[n,w,dd] = inv * sum_u f[n,1+dd,u] Wlin1[u,w]
// out[n, w] (first 128) and out[n, 128 + w*3 + dd], plus sc.
__global__ __launch_bounds__(128) void linear_kernel(
    const float* __restrict__ fbuf, const float* __restrict__ Wlin0,
    const float* __restrict__ Wlin1, const float* __restrict__ sc,
    float* __restrict__ out) {
  int n = blockIdx.x;
  int w = threadIdx.x;
  __shared__ float fs[C_];
  constexpr float inv = 0.08838834764831843f;  // 1/sqrt(128)
  float y[4];
  for (int dt = 0; dt < 4; ++dt) {
    __syncthreads();
    fs[w] = fbuf[(n * 4 + dt) * C_ + w];
    __syncthreads();
    const float* Wl = (dt == 0) ? Wlin0 : Wlin1;
    float acc = 0.f;
    #pragma unroll 8
    for (int u = 0; u < C_; ++u) acc = fmaf(fs[u], Wl[u * C_ + w], acc);
    y[dt] = acc * inv;
  }
  int base = n * 512;
  out[base + w] = y[0] + sc[base + w];
  #pragma unroll
  for (int dd = 0; dd < 3; ++dd) {
    int col = 128 + w * 3 + dd;
    out[base + col] = y[1 + dd] + sc[base + col];
  }
}

// ---------------- launcher ---------------------------------------------------
extern "C" void kernel_launch(void* const* d_in, const int* in_sizes, int n_in,
                              void* d_out, int out_size, void* d_ws, size_t ws_size,
                              hipStream_t stream) {
  const float* node_feats = (const float*)d_in[0];
  const float* sc         = (const float*)d_in[1];
  const float* node_attrs = (const float*)d_in[2];
  const float* U3_0 = (const float*)d_in[3];
  const float* U2_0 = (const float*)d_in[4];
  const float* U1_0 = (const float*)d_in[5];
  const float* W3_0 = (const float*)d_in[6];
  const float* W2_0 = (const float*)d_in[7];
  const float* W1_0 = (const float*)d_in[8];
  const float* U3_1 = (const float*)d_in[9];
  const float* U2_1 = (const float*)d_in[10];
  const float* U1_1 = (const float*)d_in[11];
  const float* W3_1 = (const float*)d_in[12];
  const float* W2_1 = (const float*)d_in[13];
  const float* W1_1 = (const float*)d_in[14];
  const float* Wlin0 = (const float*)d_in[15];
  const float* Wlin1 = (const float*)d_in[16];

  float* ws_f = (float*)d_ws;
  int*   ws_i = (int*)d_ws;

  bucket_kernel<<<1, 256, 0, stream>>>(node_attrs, ws_i + O_ELEM, ws_i + O_ORDER, ws_i + O_BOFF);

  vpre_kernel<<<(VPRE_TOTAL + 255) / 256, 256, 0, stream>>>(
      U3_0, W3_0, U2_0, W2_0, U1_0, W1_0,
      U3_1, W3_1, U2_1, W2_1, U1_1, W1_1, ws_f);

  contract_kernel<<<dim3(CHUNKS_, E_, 8), 64, 0, stream>>>(
      node_feats, ws_f, ws_i + O_ORDER, ws_i + O_BOFF, ws_f + O_F);

  linear_kernel<<<N_, C_, 0, stream>>>(ws_f + O_F, Wlin0, Wlin1, sc, (float*)d_out);
}

// Round 6
// 257.299 us; speedup vs baseline: 11.8801x; 11.8801x over previous
//
#include <hip/hip_runtime.h>
#include <hip/hip_bf16.h>

// ---------------- problem constants ----------------
namespace {
constexpr int N_ = 2048, C_ = 128, I_ = 9, E_ = 10;
constexpr int K3_ = 23, K2_ = 8, K1_ = 3;
constexpr int J3_ = 729, J2_ = 81, J1_ = 9;   // I^3, I^2, I
constexpr int M2_ = 8;                         // nodes per contraction block
constexpr int QT_ = 3;                         // q-values staged per LDS tile
constexpr int TILE_F = QT_ * I_ * C_;          // 3456 floats = 13.8 KB
constexpr int NSTAGE = (I_ * I_) / QT_;        // 27
constexpr int NCHUNK2 = (N_ + M2_ - 1) / M2_;  // 256 (covers any element skew)

// workspace layout (units: 4-byte words); total ~21 MB
constexpr int O_ELEM  = 0;            // int[N]
constexpr int O_ORDER = N_;           // int[N]  nodes sorted by element
constexpr int O_BOFF  = 2 * N_;       // int[E+1] bucket offsets
constexpr int O_V3_0  = O_BOFF + 16;
constexpr int S_V3_0  = E_ * 1 * J3_ * C_;     // 933120
constexpr int O_V3_1  = O_V3_0 + S_V3_0;
constexpr int S_V3_1  = E_ * 3 * J3_ * C_;     // 2799360
constexpr int O_V2_0  = O_V3_1 + S_V3_1;
constexpr int S_V2_0  = E_ * 1 * J2_ * C_;
constexpr int O_V2_1  = O_V2_0 + S_V2_0;
constexpr int S_V2_1  = E_ * 3 * J2_ * C_;
constexpr int O_V1_0  = O_V2_1 + S_V2_1;
constexpr int S_V1_0  = E_ * 1 * J1_ * C_;
constexpr int O_V1_1  = O_V1_0 + S_V1_0;
constexpr int S_V1_1  = E_ * 3 * J1_ * C_;
constexpr int O_F     = O_V1_1 + S_V1_1;       // float[N][4][C]
constexpr int VPRE_TOTAL = S_V3_0 + S_V3_1 + S_V2_0 + S_V2_1 + S_V1_0 + S_V1_1; // 4193280
}

// ---------------- kernel 1: bucket nodes by element (node_attrs is one-hot) --
__global__ void bucket_kernel(const float* __restrict__ attrs,
                              int* __restrict__ elem,
                              int* __restrict__ order,
                              int* __restrict__ boff) {
  __shared__ int cnt[E_], base_s[E_ + 1], cur[E_];
  int tid = threadIdx.x;
  if (tid < E_) cnt[tid] = 0;
  __syncthreads();
  for (int n = tid; n < N_; n += blockDim.x) {
    const float* a = attrs + n * E_;
    int best = 0; float bv = a[0];
    for (int e = 1; e < E_; ++e) { float v = a[e]; if (v > bv) { bv = v; best = e; } }
    elem[n] = best;
    atomicAdd(&cnt[best], 1);
  }
  __syncthreads();
  if (tid == 0) {
    int s = 0;
    for (int e = 0; e < E_; ++e) { base_s[e] = s; cur[e] = s; s += cnt[e]; }
    base_s[E_] = s;
  }
  __syncthreads();
  for (int n = tid; n < N_; n += blockDim.x) {
    int p = atomicAdd(&cur[elem[n]], 1);
    order[p] = n;
  }
  if (tid <= E_) boff[tid] = base_s[tid];
}

// ---------------- kernel 2: V[e,d,j,c] = sum_k U[d,j,k] * W[e,k,c] ----------
__device__ __forceinline__ void vpre_one(const float* __restrict__ U,
                                         const float* __restrict__ W,
                                         float* __restrict__ V,
                                         int D, int J, int K, int idx) {
  int c = idx % C_;
  int r = idx / C_;
  int j = r % J; r /= J;
  int d = r % D;
  int e = r / D;
  const float* Urow = U + (d * J + j) * K;
  const float* Wcol = W + e * K * C_ + c;
  float acc = 0.f;
  for (int k = 0; k < K; ++k) acc = fmaf(Urow[k], Wcol[k * C_], acc);
  V[idx] = acc;
}

__global__ void vpre_kernel(const float* __restrict__ U3_0, const float* __restrict__ W3_0,
                            const float* __restrict__ U2_0, const float* __restrict__ W2_0,
                            const float* __restrict__ U1_0, const float* __restrict__ W1_0,
                            const float* __restrict__ U3_1, const float* __restrict__ W3_1,
                            const float* __restrict__ U2_1, const float* __restrict__ W2_1,
                            const float* __restrict__ U1_1, const float* __restrict__ W1_1,
                            float* __restrict__ ws_f) {
  int idx = blockIdx.x * blockDim.x + threadIdx.x;
  if (idx < S_V3_0) { vpre_one(U3_0, W3_0, ws_f + O_V3_0, 1, J3_, K3_, idx); return; }
  idx -= S_V3_0;
  if (idx < S_V3_1) { vpre_one(U3_1, W3_1, ws_f + O_V3_1, 3, J3_, K3_, idx); return; }
  idx -= S_V3_1;
  if (idx < S_V2_0) { vpre_one(U2_0, W2_0, ws_f + O_V2_0, 1, J2_, K2_, idx); return; }
  idx -= S_V2_0;
  if (idx < S_V2_1) { vpre_one(U2_1, W2_1, ws_f + O_V2_1, 3, J2_, K2_, idx); return; }
  idx -= S_V2_1;
  if (idx < S_V1_0) { vpre_one(U1_0, W1_0, ws_f + O_V1_0, 1, J1_, K1_, idx); return; }
  idx -= S_V1_0;
  if (idx < S_V1_1) { vpre_one(U1_1, W1_1, ws_f + O_V1_1, 3, J1_, K1_, idx); }
}

// ---------------- kernel 3 v2: LDS-staged symmetric contraction --------------
// Per block: one (element e, irrep-slot dsel, chunk of M2_=8 same-element nodes).
// 128 threads = one channel c each. V3 consumed via LDS tiles of (1 p, 3 q)
// = 3456 floats; tile prefetched global->reg one stage ahead, committed
// reg->LDS after the barrier (async-split), so latency hides under FMAs.
__global__ __launch_bounds__(128) void contract2_kernel(
    const float* __restrict__ x, const float* __restrict__ ws_f,
    const int* __restrict__ order, const int* __restrict__ boff,
    float* __restrict__ fbuf) {
  int e = blockIdx.y;
  int dsel = blockIdx.z;
  int b0 = boff[e];
  int cnt_e = boff[e + 1] - b0;
  int base = blockIdx.x * M2_;
  if (base >= cnt_e) return;
  int cnt = cnt_e - base; if (cnt > M2_) cnt = M2_;
  int t = threadIdx.x;      // == channel c
  int c = t;

  __shared__ float tile[TILE_F];

  const float* V3; const float* V2; const float* V1;
  if (dsel == 0) {
    V3 = ws_f + O_V3_0 + e * J3_ * C_;
    V2 = ws_f + O_V2_0 + e * J2_ * C_;
    V1 = ws_f + O_V1_0 + e * J1_ * C_;
  } else {
    int d = dsel - 1;
    V3 = ws_f + O_V3_1 + (e * 3 + d) * J3_ * C_;
    V2 = ws_f + O_V2_1 + (e * 3 + d) * J2_ * C_;
    V1 = ws_f + O_V1_1 + (e * 3 + d) * J1_ * C_;
  }

  int nn[M2_];
  #pragma unroll
  for (int m = 0; m < M2_; ++m) {
    int idx = base + m; if (idx >= cnt_e) idx = cnt_e - 1;
    nn[m] = order[b0 + idx];
  }
  float xm[M2_][I_];
  #pragma unroll
  for (int m = 0; m < M2_; ++m) {
    const float* xp = x + (nn[m] * C_ + c) * I_;
    #pragma unroll
    for (int i = 0; i < I_; ++i) xm[m][i] = xp[i];
  }

  float f[M2_];
  #pragma unroll
  for (int m = 0; m < M2_; ++m) f[m] = 0.f;

  // ---- prefetch stage 0 tile into registers (864 float4 over 128 threads) --
  float4 pf[7];
  {
    const float4* s4 = (const float4*)V3;
    #pragma unroll
    for (int r = 0; r < 6; ++r) pf[r] = s4[r * 128 + t];
    if (t < 96) pf[6] = s4[6 * 128 + t];
  }
  // prefetch V2 for stage 0 (pq = 0,1,2)
  float v2pf[QT_];
  #pragma unroll
  for (int j = 0; j < QT_; ++j) v2pf[j] = V2[j * C_ + c];

  float ap[M2_];
  for (int p = 0; p < I_; ++p) {
    float v1p = V1[p * C_ + c];   // used 3 stages later -> latency hidden
    #pragma unroll
    for (int m = 0; m < M2_; ++m) ap[m] = 0.f;
    for (int qt = 0; qt < QT_; ++qt) {
      int s = p * QT_ + qt;
      __syncthreads();            // LDS free (prev stage consumed)
      // commit prefetched regs to LDS
      float4* l4 = (float4*)tile;
      #pragma unroll
      for (int r = 0; r < 6; ++r) l4[r * 128 + t] = pf[r];
      if (t < 96) l4[6 * 128 + t] = pf[6];
      // grab current-stage V2 values, then prefetch next stage
      float v2c[QT_];
      #pragma unroll
      for (int j = 0; j < QT_; ++j) v2c[j] = v2pf[j];
      if (s + 1 < NSTAGE) {
        const float4* s4 = (const float4*)(V3 + (s + 1) * TILE_F);
        #pragma unroll
        for (int r = 0; r < 6; ++r) pf[r] = s4[r * 128 + t];
        if (t < 96) pf[6] = s4[6 * 128 + t];
        #pragma unroll
        for (int j = 0; j < QT_; ++j) v2pf[j] = V2[((s + 1) * QT_ + j) * C_ + c];
      }
      __syncthreads();            // LDS tile ready
      int qs = qt * QT_;
      #pragma unroll
      for (int j = 0; j < QT_; ++j) {
        int q = qs + j;
        float tt[M2_];
        #pragma unroll
        for (int m = 0; m < M2_; ++m) tt[m] = v2c[j];
        #pragma unroll
        for (int i = 0; i < I_; ++i) {
          float v = tile[(j * I_ + i) * C_ + c];
          #pragma unroll
          for (int m = 0; m < M2_; ++m) tt[m] = fmaf(xm[m][i], v, tt[m]);
        }
        #pragma unroll
        for (int m = 0; m < M2_; ++m) ap[m] = fmaf(tt[m], xm[m][q], ap[m]);
      }
    }
    #pragma unroll
    for (int m = 0; m < M2_; ++m) f[m] = fmaf(ap[m] + v1p, xm[m][p], f[m]);
  }

  #pragma unroll
  for (int m = 0; m < M2_; ++m)
    if (m < cnt) fbuf[(nn[m] * 4 + dsel) * C_ + c] = f[m];
}

// ---------------- kernel 4: equivariant linear + skip ------------------------
__global__ __launch_bounds__(128) void linear_kernel(
    const float* __restrict__ fbuf, const float* __restrict__ Wlin0,
    const float* __restrict__ Wlin1, const float* __restrict__ sc,
    float* __restrict__ out) {
  int n = blockIdx.x;
  int w = threadIdx.x;
  __shared__ float fs[C_];
  constexpr float inv = 0.08838834764831843f;  // 1/sqrt(128)
  float y[4];
  for (int dt = 0; dt < 4; ++dt) {
    __syncthreads();
    fs[w] = fbuf[(n * 4 + dt) * C_ + w];
    __syncthreads();
    const float* Wl = (dt == 0) ? Wlin0 : Wlin1;
    float acc = 0.f;
    #pragma unroll 8
    for (int u = 0; u < C_; ++u) acc = fmaf(fs[u], Wl[u * C_ + w], acc);
    y[dt] = acc * inv;
  }
  int base = n * 512;
  out[base + w] = y[0] + sc[base + w];
  #pragma unroll
  for (int dd = 0; dd < 3; ++dd) {
    int col = 128 + w * 3 + dd;
    out[base + col] = y[1 + dd] + sc[base + col];
  }
}

// ---------------- launcher ---------------------------------------------------
extern "C" void kernel_launch(void* const* d_in, const int* in_sizes, int n_in,
                              void* d_out, int out_size, void* d_ws, size_t ws_size,
                              hipStream_t stream) {
  const float* node_feats = (const float*)d_in[0];
  const float* sc         = (const float*)d_in[1];
  const float* node_attrs = (const float*)d_in[2];
  const float* U3_0 = (const float*)d_in[3];
  const float* U2_0 = (const float*)d_in[4];
  const float* U1_0 = (const float*)d_in[5];
  const float* W3_0 = (const float*)d_in[6];
  const float* W2_0 = (const float*)d_in[7];
  const float* W1_0 = (const float*)d_in[8];
  const float* U3_1 = (const float*)d_in[9];
  const float* U2_1 = (const float*)d_in[10];
  const float* U1_1 = (const float*)d_in[11];
  const float* W3_1 = (const float*)d_in[12];
  const float* W2_1 = (const float*)d_in[13];
  const float* W1_1 = (const float*)d_in[14];
  const float* Wlin0 = (const float*)d_in[15];
  const float* Wlin1 = (const float*)d_in[16];

  float* ws_f = (float*)d_ws;
  int*   ws_i = (int*)d_ws;

  bucket_kernel<<<1, 256, 0, stream>>>(node_attrs, ws_i + O_ELEM, ws_i + O_ORDER, ws_i + O_BOFF);

  vpre_kernel<<<(VPRE_TOTAL + 255) / 256, 256, 0, stream>>>(
      U3_0, W3_0, U2_0, W2_0, U1_0, W1_0,
      U3_1, W3_1, U2_1, W2_1, U1_1, W1_1, ws_f);

  contract2_kernel<<<dim3(NCHUNK2, E_, 4), 128, 0, stream>>>(
      node_feats, ws_f, ws_i + O_ORDER, ws_i + O_BOFF, ws_f + O_F);

  linear_kernel<<<N_, C_, 0, stream>>>(ws_f + O_F, Wlin0, Wlin1, sc, (float*)d_out);
}

// Round 7
// 113.507 us; speedup vs baseline: 26.9301x; 2.2668x over previous
//
#include <hip/hip_runtime.h>
#include <hip/hip_bf16.h>

// ---------------- problem constants ----------------
namespace {
constexpr int N_ = 2048, C_ = 128, I_ = 9, E_ = 10;
constexpr int J3_ = 729, J2_ = 81, J1_ = 9;   // I^3, I^2, I
constexpr int M3_ = 8;                         // nodes per contraction block
constexpr int NCHUNK3 = 64;                    // chunks per element (512 nodes max/elem, safe)

// workspace layout (units: 4-byte words)
constexpr int O_ELEM  = 0;            // int[N]
constexpr int O_ORDER = N_;           // int[N]  nodes sorted by element
constexpr int O_BOFF  = 2 * N_;       // int[E+1] bucket offsets
constexpr int O_V3_0  = O_BOFF + 16;
constexpr int S_V3_0  = E_ * 1 * J3_ * C_;     // 933120
constexpr int O_V3_1  = O_V3_0 + S_V3_0;
constexpr int S_V3_1  = E_ * 3 * J3_ * C_;     // 2799360
constexpr int O_V2_0  = O_V3_1 + S_V3_1;
constexpr int S_V2_0  = E_ * 1 * J2_ * C_;
constexpr int O_V2_1  = O_V2_0 + S_V2_0;
constexpr int S_V2_1  = E_ * 3 * J2_ * C_;
constexpr int O_V1_0  = O_V2_1 + S_V2_1;
constexpr int S_V1_0  = E_ * 1 * J1_ * C_;
constexpr int O_V1_1  = O_V1_0 + S_V1_0;
constexpr int S_V1_1  = E_ * 3 * J1_ * C_;
constexpr int O_F     = O_V1_1 + S_V1_1;       // float[N][4][C]
constexpr int VPRE_TOTAL = S_V3_0 + S_V3_1 + S_V2_0 + S_V2_1 + S_V1_0 + S_V1_1; // 4193280
}

// ---------------- kernel 1: bucket nodes by element (node_attrs is one-hot) --
__global__ void bucket_kernel(const float* __restrict__ attrs,
                              int* __restrict__ elem,
                              int* __restrict__ order,
                              int* __restrict__ boff) {
  __shared__ int cnt[E_], base_s[E_ + 1], cur[E_];
  int tid = threadIdx.x;
  if (tid < E_) cnt[tid] = 0;
  __syncthreads();
  for (int n = tid; n < N_; n += blockDim.x) {
    const float* a = attrs + n * E_;
    int best = 0; float bv = a[0];
    for (int e = 1; e < E_; ++e) { float v = a[e]; if (v > bv) { bv = v; best = e; } }
    elem[n] = best;
    atomicAdd(&cnt[best], 1);
  }
  __syncthreads();
  if (tid == 0) {
    int s = 0;
    for (int e = 0; e < E_; ++e) { base_s[e] = s; cur[e] = s; s += cnt[e]; }
    base_s[E_] = s;
  }
  __syncthreads();
  for (int n = tid; n < N_; n += blockDim.x) {
    int p = atomicAdd(&cur[elem[n]], 1);
    order[p] = n;
  }
  if (tid <= E_) boff[tid] = base_s[tid];
}

// ---------------- kernel 2 v2: V[e,d,j,c] = sum_k U[d,j,k]*W[e,k,c], float4 --
__device__ __forceinline__ void vpre_one4(const float* __restrict__ U,
                                          const float* __restrict__ W,
                                          float* __restrict__ V,
                                          int D, int J, int K, int q) {
  constexpr int C4 = C_ / 4;
  int c4 = q % C4;
  int r = q / C4;
  int j = r % J; r /= J;
  int d = r % D;
  int e = r / D;
  const float* Urow = U + (d * J + j) * K;
  const float* Wb = W + e * K * C_ + c4 * 4;
  float4 acc = make_float4(0.f, 0.f, 0.f, 0.f);
  for (int k = 0; k < K; ++k) {
    float u = Urow[k];
    float4 wv = *(const float4*)(Wb + k * C_);
    acc.x = fmaf(u, wv.x, acc.x);
    acc.y = fmaf(u, wv.y, acc.y);
    acc.z = fmaf(u, wv.z, acc.z);
    acc.w = fmaf(u, wv.w, acc.w);
  }
  ((float4*)V)[q] = acc;
}

__global__ void vpre_kernel(const float* __restrict__ U3_0, const float* __restrict__ W3_0,
                            const float* __restrict__ U2_0, const float* __restrict__ W2_0,
                            const float* __restrict__ U1_0, const float* __restrict__ W1_0,
                            const float* __restrict__ U3_1, const float* __restrict__ W3_1,
                            const float* __restrict__ U2_1, const float* __restrict__ W2_1,
                            const float* __restrict__ U1_1, const float* __restrict__ W1_1,
                            float* __restrict__ ws_f) {
  int idx = blockIdx.x * blockDim.x + threadIdx.x;   // over VPRE_TOTAL/4
  if (idx < S_V3_0 / 4) { vpre_one4(U3_0, W3_0, ws_f + O_V3_0, 1, J3_, 23, idx); return; }
  idx -= S_V3_0 / 4;
  if (idx < S_V3_1 / 4) { vpre_one4(U3_1, W3_1, ws_f + O_V3_1, 3, J3_, 23, idx); return; }
  idx -= S_V3_1 / 4;
  if (idx < S_V2_0 / 4) { vpre_one4(U2_0, W2_0, ws_f + O_V2_0, 1, J2_, 8, idx); return; }
  idx -= S_V2_0 / 4;
  if (idx < S_V2_1 / 4) { vpre_one4(U2_1, W2_1, ws_f + O_V2_1, 3, J2_, 8, idx); return; }
  idx -= S_V2_1 / 4;
  if (idx < S_V1_0 / 4) { vpre_one4(U1_0, W1_0, ws_f + O_V1_0, 1, J1_, 3, idx); return; }
  idx -= S_V1_0 / 4;
  if (idx < S_V1_1 / 4) { vpre_one4(U1_1, W1_1, ws_f + O_V1_1, 3, J1_, 3, idx); }
}

// ---------------- kernel 3 v3: barrier-free direct-load contraction ----------
// grid: x = chunk*8 + (slab&7)  [gridDim.x = NCHUNK3*8, multiple of 8 so
//       flattened_id % 8 == slab % 8 -> each (e,dsel) slab pinned to one XCD;
//       5 slabs x 373KB = 1.9MB resident per XCD L2], y = slab>>3 (5).
// block: 128 threads = one channel each; M3_=8 same-element nodes.
// V3 loads are scalar + coalesced (lane c -> address ..*C + c); no LDS, no
// barriers -> compiler pipelines loads across the whole pq loop.
__global__ __launch_bounds__(128) void contract3_kernel(
    const float* __restrict__ x, const float* __restrict__ ws_f,
    const int* __restrict__ order, const int* __restrict__ boff,
    float* __restrict__ fbuf) {
  int slab = (blockIdx.x & 7) + 8 * blockIdx.y;   // 0..39
  int chunk = blockIdx.x >> 3;
  int e = slab >> 2;
  int dsel = slab & 3;
  int b0 = boff[e];
  int cnt_e = boff[e + 1] - b0;
  int base = chunk * M3_;
  if (base >= cnt_e) return;
  int cnt = cnt_e - base; if (cnt > M3_) cnt = M3_;
  int c = threadIdx.x;

  const float* V3; const float* V2; const float* V1;
  if (dsel == 0) {
    V3 = ws_f + O_V3_0 + e * J3_ * C_;
    V2 = ws_f + O_V2_0 + e * J2_ * C_;
    V1 = ws_f + O_V1_0 + e * J1_ * C_;
  } else {
    int d = dsel - 1;
    V3 = ws_f + O_V3_1 + (e * 3 + d) * J3_ * C_;
    V2 = ws_f + O_V2_1 + (e * 3 + d) * J2_ * C_;
    V1 = ws_f + O_V1_1 + (e * 3 + d) * J1_ * C_;
  }

  int nn[M3_];
  #pragma unroll
  for (int m = 0; m < M3_; ++m) {
    int idx = base + m; if (idx >= cnt_e) idx = cnt_e - 1;
    nn[m] = order[b0 + idx];
  }
  float xm[M3_][I_];
  #pragma unroll
  for (int m = 0; m < M3_; ++m) {
    const float* xp = x + (nn[m] * C_ + c) * I_;
    #pragma unroll
    for (int i = 0; i < I_; ++i) xm[m][i] = xp[i];
  }

  float f[M3_];
  #pragma unroll
  for (int m = 0; m < M3_; ++m) f[m] = 0.f;

  for (int p = 0; p < I_; ++p) {
    float ap[M3_];
    #pragma unroll
    for (int m = 0; m < M3_; ++m) ap[m] = 0.f;
    #pragma unroll
    for (int q = 0; q < I_; ++q) {
      int pq = p * I_ + q;
      float v2 = V2[pq * C_ + c];
      float vv[I_];
      #pragma unroll
      for (int i = 0; i < I_; ++i) vv[i] = V3[(pq * I_ + i) * C_ + c];
      float t[M3_];
      #pragma unroll
      for (int m = 0; m < M3_; ++m) t[m] = v2;
      #pragma unroll
      for (int i = 0; i < I_; ++i) {
        #pragma unroll
        for (int m = 0; m < M3_; ++m) t[m] = fmaf(xm[m][i], vv[i], t[m]);
      }
      #pragma unroll
      for (int m = 0; m < M3_; ++m) ap[m] = fmaf(t[m], xm[m][q], ap[m]);
    }
    float v1 = V1[p * C_ + c];
    #pragma unroll
    for (int m = 0; m < M3_; ++m) f[m] = fmaf(ap[m] + v1, xm[m][p], f[m]);
  }

  #pragma unroll
  for (int m = 0; m < M3_; ++m)
    if (m < cnt) fbuf[(nn[m] * 4 + dsel) * C_ + c] = f[m];
}

// ---------------- kernel 4 v2: equivariant linear + skip, 8 nodes/block ------
__global__ __launch_bounds__(128) void linear2_kernel(
    const float* __restrict__ fbuf, const float* __restrict__ Wlin0,
    const float* __restrict__ Wlin1, const float* __restrict__ sc,
    float* __restrict__ out) {
  constexpr int NB = 8;
  int nb = blockIdx.x * NB;
  int w = threadIdx.x;
  __shared__ float fs[NB][C_];
  constexpr float inv = 0.08838834764831843f;  // 1/sqrt(128)
  for (int dt = 0; dt < 4; ++dt) {
    #pragma unroll
    for (int r = 0; r < NB; ++r) fs[r][w] = fbuf[((nb + r) * 4 + dt) * C_ + w];
    __syncthreads();
    const float* Wl = (dt == 0) ? Wlin0 : Wlin1;
    float acc[NB];
    #pragma unroll
    for (int r = 0; r < NB; ++r) acc[r] = 0.f;
    for (int u = 0; u < C_; ++u) {
      float wv = Wl[u * C_ + w];
      #pragma unroll
      for (int r = 0; r < NB; ++r) acc[r] = fmaf(fs[r][u], wv, acc[r]);
    }
    if (dt == 0) {
      #pragma unroll
      for (int r = 0; r < NB; ++r) {
        int o = (nb + r) * 512 + w;
        out[o] = acc[r] * inv + sc[o];
      }
    } else {
      int col = 128 + w * 3 + (dt - 1);
      #pragma unroll
      for (int r = 0; r < NB; ++r) {
        int o = (nb + r) * 512 + col;
        out[o] = acc[r] * inv + sc[o];
      }
    }
    __syncthreads();
  }
}

// ---------------- launcher ---------------------------------------------------
extern "C" void kernel_launch(void* const* d_in, const int* in_sizes, int n_in,
                              void* d_out, int out_size, void* d_ws, size_t ws_size,
                              hipStream_t stream) {
  const float* node_feats = (const float*)d_in[0];
  const float* sc         = (const float*)d_in[1];
  const float* node_attrs = (const float*)d_in[2];
  const float* U3_0 = (const float*)d_in[3];
  const float* U2_0 = (const float*)d_in[4];
  const float* U1_0 = (const float*)d_in[5];
  const float* W3_0 = (const float*)d_in[6];
  const float* W2_0 = (const float*)d_in[7];
  const float* W1_0 = (const float*)d_in[8];
  const float* U3_1 = (const float*)d_in[9];
  const float* U2_1 = (const float*)d_in[10];
  const float* U1_1 = (const float*)d_in[11];
  const float* W3_1 = (const float*)d_in[12];
  const float* W2_1 = (const float*)d_in[13];
  const float* W1_1 = (const float*)d_in[14];
  const float* Wlin0 = (const float*)d_in[15];
  const float* Wlin1 = (const float*)d_in[16];

  float* ws_f = (float*)d_ws;
  int*   ws_i = (int*)d_ws;

  bucket_kernel<<<1, 256, 0, stream>>>(node_attrs, ws_i + O_ELEM, ws_i + O_ORDER, ws_i + O_BOFF);

  vpre_kernel<<<(VPRE_TOTAL / 4 + 255) / 256, 256, 0, stream>>>(
      U3_0, W3_0, U2_0, W2_0, U1_0, W1_0,
      U3_1, W3_1, U2_1, W2_1, U1_1, W1_1, ws_f);

  contract3_kernel<<<dim3(NCHUNK3 * 8, 5, 1), 128, 0, stream>>>(
      node_feats, ws_f, ws_i + O_ORDER, ws_i + O_BOFF, ws_f + O_F);

  linear2_kernel<<<N_ / 8, C_, 0, stream>>>(ws_f + O_F, Wlin0, Wlin1, sc, (float*)d_out);
}

// Round 8
// 74.843 us; speedup vs baseline: 40.8423x; 1.5166x over previous
//
#include <hip/hip_runtime.h>
#include <hip/hip_bf16.h>

// ---------------- problem constants ----------------
namespace {
constexpr int N_ = 2048, C_ = 128, I_ = 9, E_ = 10;
constexpr int NSLAB = 40;            // (e, dsel): e*4 + dsel ; dsel 0 = irrep0, 1..3 = irrep1 rows
constexpr int M_ = 8;                // nodes per contraction block
constexpr int NCHUNK = 40;           // chunks/element (320-node cap per element, safe for N=2048,E=10)

// workspace layout (units: 4-byte words); total ~24.3 MB
constexpr int O_ELEM  = 0;                       // (unused slot kept for layout clarity)
constexpr int O_ORDER = N_;                      // int[N] nodes sorted by element
constexpr int O_BOFF  = 2 * N_;                  // int[E+1]
constexpr int O_V3T   = O_BOFF + 16;             // [slab][81][C][12] : {V2, V3 i=0..8, 0, 0}
constexpr int S_V3T   = NSLAB * 81 * C_ * 12;    // 4,976,640
constexpr int O_V1T   = O_V3T + S_V3T;           // [slab][9][C]
constexpr int S_V1T   = NSLAB * 9 * C_;          // 46,080
constexpr int O_F     = O_V1T + S_V1T;           // float[N][4][C]
}

// ---------------- kernel 1: bucket nodes by element (one-hot attrs) ----------
__global__ __launch_bounds__(1024) void bucket_kernel(const float* __restrict__ attrs,
                                                      int* __restrict__ order,
                                                      int* __restrict__ boff) {
  __shared__ int cnt[E_], base_s[E_ + 1], cur[E_];
  __shared__ short elem_s[N_];
  int tid = threadIdx.x;
  if (tid < E_) cnt[tid] = 0;
  __syncthreads();
  for (int n = tid; n < N_; n += 1024) {
    const float* a = attrs + n * E_;
    int best = 0; float bv = a[0];
    for (int e = 1; e < E_; ++e) { float v = a[e]; if (v > bv) { bv = v; best = e; } }
    elem_s[n] = (short)best;
    atomicAdd(&cnt[best], 1);
  }
  __syncthreads();
  if (tid == 0) {
    int s = 0;
    for (int e = 0; e < E_; ++e) { base_s[e] = s; cur[e] = s; s += cnt[e]; }
    base_s[E_] = s;
  }
  __syncthreads();
  for (int n = tid; n < N_; n += 1024) {
    int p = atomicAdd(&cur[elem_s[n]], 1);
    order[p] = n;
  }
  if (tid <= E_) boff[tid] = base_s[tid];
}

// ---------------- kernel 2 v3: emit packed V-slots directly ------------------
// grid (82, NSLAB), block 128 = channel c.
// blockIdx.x = pq (0..80): slot[(slab*81+pq)*C+c][0..11] = {V2, V3 i0..i8, 0, 0}
// blockIdx.x = 81       : V1T[slab][p][c], p = 0..8
// U-row loads are wave-uniform -> scalar; W loads coalesced over c.
__global__ __launch_bounds__(128) void vpre3_kernel(
    const float* __restrict__ U3_0, const float* __restrict__ U2_0, const float* __restrict__ U1_0,
    const float* __restrict__ W3_0, const float* __restrict__ W2_0, const float* __restrict__ W1_0,
    const float* __restrict__ U3_1, const float* __restrict__ U2_1, const float* __restrict__ U1_1,
    const float* __restrict__ W3_1, const float* __restrict__ W2_1, const float* __restrict__ W1_1,
    float* __restrict__ ws_f) {
  int slab = blockIdx.y;
  int e = slab >> 2, dsel = slab & 3;
  int d = (dsel == 0) ? 0 : dsel - 1;
  const float *U3, *U2, *U1, *W3, *W2, *W1;
  if (dsel == 0) { U3 = U3_0; U2 = U2_0; U1 = U1_0; W3 = W3_0; W2 = W2_0; W1 = W1_0; }
  else           { U3 = U3_1; U2 = U2_1; U1 = U1_1; W3 = W3_1; W2 = W2_1; W1 = W1_1; }
  int c = threadIdx.x;
  int pq = blockIdx.x;
  if (pq < 81) {
    const float* U3r = U3 + (d * 729 + pq * 9) * 23;   // [i][k] contiguous
    const float* U2r = U2 + (d * 81 + pq) * 8;
    float acc[9];
    #pragma unroll
    for (int i = 0; i < 9; ++i) acc[i] = 0.f;
    #pragma unroll
    for (int k = 0; k < 23; ++k) {
      float w = W3[(e * 23 + k) * C_ + c];
      #pragma unroll
      for (int i = 0; i < 9; ++i) acc[i] = fmaf(U3r[i * 23 + k], w, acc[i]);
    }
    float a2 = 0.f;
    #pragma unroll
    for (int k = 0; k < 8; ++k) a2 = fmaf(U2r[k], W2[(e * 8 + k) * C_ + c], a2);
    float4* dst = (float4*)(ws_f + O_V3T + ((size_t)(slab * 81 + pq) * C_ + c) * 12);
    dst[0] = make_float4(a2, acc[0], acc[1], acc[2]);
    dst[1] = make_float4(acc[3], acc[4], acc[5], acc[6]);
    dst[2] = make_float4(acc[7], acc[8], 0.f, 0.f);
  } else {
    #pragma unroll
    for (int p = 0; p < 9; ++p) {
      float a = 0.f;
      #pragma unroll
      for (int k = 0; k < 3; ++k) a = fmaf(U1[(d * 9 + p) * 3 + k], W1[(e * 3 + k) * C_ + c], a);
      ws_f[O_V1T + (slab * 9 + p) * C_ + c] = a;
    }
  }
}

// ---------------- kernel 3 v4: pq-split contraction, packed float4 loads -----
// f(n,c,slab) = sum_pq x[p]*x[q]*(V2[pq] + sum_i x[i]*V3[pq,i]) + sum_p x[p]*V1[p]
// Block: 256 thr = (s in {0,1}) x (c = 0..127); wave-half s takes pq range;
// LDS-reduce at end. Grid x = chunk*8 + (slab&7) pins each slab to one XCD.
template<int PQ0, int PQ1>
__device__ __forceinline__ void accum_range(const float4* __restrict__ v3t,
                                            const float (&xm)[M_][I_],
                                            float (&f)[M_], int c) {
  #pragma unroll
  for (int pq = PQ0; pq < PQ1; ++pq) {
    int p = pq / 9, q = pq % 9;
    const float4* sp = v3t + (pq * C_ + c) * 3;
    float4 f0 = sp[0], f1 = sp[1], f2 = sp[2];
    float t[M_];
    #pragma unroll
    for (int m = 0; m < M_; ++m) t[m] = f0.x;                 // V2
    #pragma unroll
    for (int m = 0; m < M_; ++m) {
      t[m] = fmaf(xm[m][0], f0.y, t[m]);
      t[m] = fmaf(xm[m][1], f0.z, t[m]);
      t[m] = fmaf(xm[m][2], f0.w, t[m]);
      t[m] = fmaf(xm[m][3], f1.x, t[m]);
      t[m] = fmaf(xm[m][4], f1.y, t[m]);
      t[m] = fmaf(xm[m][5], f1.z, t[m]);
      t[m] = fmaf(xm[m][6], f1.w, t[m]);
      t[m] = fmaf(xm[m][7], f2.x, t[m]);
      t[m] = fmaf(xm[m][8], f2.y, t[m]);
    }
    #pragma unroll
    for (int m = 0; m < M_; ++m) f[m] = fmaf(t[m] * xm[m][q], xm[m][p], f[m]);
  }
}

__global__ __launch_bounds__(256) void contract4_kernel(
    const float* __restrict__ x, const float* __restrict__ ws_f,
    const int* __restrict__ order, const int* __restrict__ boff,
    float* __restrict__ fbuf) {
  int slab = (blockIdx.x & 7) + 8 * blockIdx.y;   // 0..39, pinned to XCD (x&7)
  int chunk = blockIdx.x >> 3;
  int e = slab >> 2, dsel = slab & 3;
  int b0 = boff[e];
  int cnt_e = boff[e + 1] - b0;
  int base = chunk * M_;
  if (base >= cnt_e) return;                      // block-uniform
  int cnt = cnt_e - base; if (cnt > M_) cnt = M_;
  int t = threadIdx.x;
  int c = t & 127, s = t >> 7;

  const float4* v3t = (const float4*)(ws_f + O_V3T + (size_t)slab * 81 * C_ * 12);
  const float*  v1  = ws_f + O_V1T + slab * 9 * C_;

  int nn[M_];
  #pragma unroll
  for (int m = 0; m < M_; ++m) {
    int idx = base + m; if (idx >= cnt_e) idx = cnt_e - 1;
    nn[m] = order[b0 + idx];
  }
  float xm[M_][I_];
  #pragma unroll
  for (int m = 0; m < M_; ++m) {
    const float* xp = x + (nn[m] * C_ + c) * I_;
    #pragma unroll
    for (int i = 0; i < I_; ++i) xm[m][i] = xp[i];
  }
  float f[M_];
  #pragma unroll
  for (int m = 0; m < M_; ++m) f[m] = 0.f;

  __shared__ float red[C_][M_ + 1];               // +1 pad: conflict-free

  if (s == 0) {
    accum_range<0, 41>(v3t, xm, f, c);
    #pragma unroll
    for (int p = 0; p < 9; ++p) {
      float v = v1[p * C_ + c];
      #pragma unroll
      for (int m = 0; m < M_; ++m) f[m] = fmaf(xm[m][p], v, f[m]);
    }
  } else {
    accum_range<41, 81>(v3t, xm, f, c);
    #pragma unroll
    for (int m = 0; m < M_; ++m) red[c][m] = f[m];
  }
  __syncthreads();
  if (s == 0) {
    #pragma unroll
    for (int m = 0; m < M_; ++m) f[m] += red[c][m];
    #pragma unroll
    for (int m = 0; m < M_; ++m)
      if (m < cnt) fbuf[(nn[m] * 4 + dsel) * C_ + c] = f[m];
  }
}

// ---------------- kernel 4 v3: equivariant linear + skip, dt-split -----------
__global__ __launch_bounds__(128) void linear3_kernel(
    const float* __restrict__ fbuf, const float* __restrict__ Wlin0,
    const float* __restrict__ Wlin1, const float* __restrict__ sc,
    float* __restrict__ out) {
  constexpr int NB = 8;
  int dt = blockIdx.y;
  int nb = blockIdx.x * NB;
  int w = threadIdx.x;
  __shared__ float fs[NB][C_];
  constexpr float inv = 0.08838834764831843f;  // 1/sqrt(128)
  #pragma unroll
  for (int r = 0; r < NB; ++r) fs[r][w] = fbuf[((nb + r) * 4 + dt) * C_ + w];
  __syncthreads();
  const float* Wl = (dt == 0) ? Wlin0 : Wlin1;
  float acc[NB];
  #pragma unroll
  for (int r = 0; r < NB; ++r) acc[r] = 0.f;
  for (int u = 0; u < C_; ++u) {
    float wv = Wl[u * C_ + w];
    #pragma unroll
    for (int r = 0; r < NB; ++r) acc[r] = fmaf(fs[r][u], wv, acc[r]);
  }
  if (dt == 0) {
    #pragma unroll
    for (int r = 0; r < NB; ++r) { int o = (nb + r) * 512 + w; out[o] = acc[r] * inv + sc[o]; }
  } else {
    int col = 128 + w * 3 + (dt - 1);
    #pragma unroll
    for (int r = 0; r < NB; ++r) { int o = (nb + r) * 512 + col; out[o] = acc[r] * inv + sc[o]; }
  }
}

// ---------------- launcher ---------------------------------------------------
extern "C" void kernel_launch(void* const* d_in, const int* in_sizes, int n_in,
                              void* d_out, int out_size, void* d_ws, size_t ws_size,
                              hipStream_t stream) {
  const float* node_feats = (const float*)d_in[0];
  const float* sc         = (const float*)d_in[1];
  const float* node_attrs = (const float*)d_in[2];
  const float* U3_0 = (const float*)d_in[3];
  const float* U2_0 = (const float*)d_in[4];
  const float* U1_0 = (const float*)d_in[5];
  const float* W3_0 = (const float*)d_in[6];
  const float* W2_0 = (const float*)d_in[7];
  const float* W1_0 = (const float*)d_in[8];
  const float* U3_1 = (const float*)d_in[9];
  const float* U2_1 = (const float*)d_in[10];
  const float* U1_1 = (const float*)d_in[11];
  const float* W3_1 = (const float*)d_in[12];
  const float* W2_1 = (const float*)d_in[13];
  const float* W1_1 = (const float*)d_in[14];
  const float* Wlin0 = (const float*)d_in[15];
  const float* Wlin1 = (const float*)d_in[16];

  float* ws_f = (float*)d_ws;
  int*   ws_i = (int*)d_ws;

  bucket_kernel<<<1, 1024, 0, stream>>>(node_attrs, ws_i + O_ORDER, ws_i + O_BOFF);

  vpre3_kernel<<<dim3(82, NSLAB), 128, 0, stream>>>(
      U3_0, U2_0, U1_0, W3_0, W2_0, W1_0,
      U3_1, U2_1, U1_1, W3_1, W2_1, W1_1, ws_f);

  contract4_kernel<<<dim3(NCHUNK * 8, 5), 256, 0, stream>>>(
      node_feats, ws_f, ws_i + O_ORDER, ws_i + O_BOFF, ws_f + O_F);

  linear3_kernel<<<dim3(N_ / 8, 4), 128, 0, stream>>>(ws_f + O_F, Wlin0, Wlin1, sc, (float*)d_out);
}

// Round 9
// 54.119 us; speedup vs baseline: 56.4819x; 1.3829x over previous
//
#include <hip/hip_runtime.h>
#include <hip/hip_bf16.h>

// ---------------- problem constants ----------------
namespace {
constexpr int N_ = 2048, C_ = 128, I_ = 9, E_ = 10;
constexpr int NSLAB = 40;            // (e, dsel)
constexpr int M_ = 8;                // nodes per contraction block
constexpr int NCHUNK = 40;           // chunks/element (320-node cap, safe)
constexpr int NT3 = 165;             // #sorted triples p<=q<=i
constexpr int NT2 = 45;              // #sorted pairs p<=q

// workspace layout (units: 4-byte words)
constexpr int O_ORDER = N_;                      // int[N] nodes sorted by element
constexpr int O_BOFF  = 2 * N_;                  // int[E+1]
constexpr int O_U3S   = O_BOFF + 16;             // [4][165][23]
constexpr int S_U3S   = 4 * NT3 * 23;            // 15180
constexpr int O_U2S   = O_U3S + S_U3S;           // [4][45][8]
constexpr int S_U2S   = 4 * NT2 * 8;             // 1440
constexpr int O_A     = O_U2S + S_U2S;           // V2S: [slab][12][C][4]  (48 slots, 45 used)
constexpr int S_A     = NSLAB * 12 * C_ * 4;     // 245760
constexpr int O_B     = O_A + S_A;               // V3S: [slab][42][C][4]  (168 slots, 165 used)
constexpr int S_B     = NSLAB * 42 * C_ * 4;     // 860160
constexpr int O_C     = O_B + S_B;               // V1 : [slab][3][C][4]   (12 slots, 9 used)
constexpr int S_C     = NSLAB * 3 * C_ * 4;      // 61440
constexpr int O_F     = O_C + S_C;               // float[N][4][C]
}

__device__ __forceinline__ float f4lane(float4 v, int l) {
  return l == 0 ? v.x : l == 1 ? v.y : l == 2 ? v.z : v.w;
}

// ---------------- kernel 1: bucket nodes by element (one-hot attrs) ----------
__global__ __launch_bounds__(1024) void bucket_kernel(const float* __restrict__ attrs,
                                                      int* __restrict__ order,
                                                      int* __restrict__ boff) {
  __shared__ int cnt[E_], base_s[E_ + 1], cur[E_];
  __shared__ short elem_s[N_];
  int tid = threadIdx.x;
  if (tid < E_) cnt[tid] = 0;
  __syncthreads();
  for (int n = tid; n < N_; n += 1024) {
    const float* a = attrs + n * E_;
    int best = 0; float bv = a[0];
    for (int e = 1; e < E_; ++e) { float v = a[e]; if (v > bv) { bv = v; best = e; } }
    elem_s[n] = (short)best;
    atomicAdd(&cnt[best], 1);
  }
  __syncthreads();
  if (tid == 0) {
    int s = 0;
    for (int e = 0; e < E_; ++e) { base_s[e] = s; cur[e] = s; s += cnt[e]; }
    base_s[E_] = s;
  }
  __syncthreads();
  for (int n = tid; n < N_; n += 1024) {
    int p = atomicAdd(&cur[elem_s[n]], 1);
    order[p] = n;
  }
  if (tid <= E_) boff[tid] = base_s[tid];
}

// ---------------- kernel 1b: symmetric-fold U tensors ------------------------
// U3S[d4][t][k] = sum over distinct perms of sorted triple t of U3[d, ., ., ., k]
// U2S[d4][j][k] = sum over distinct perms of sorted pair j of U2[d, ., ., k]
__global__ __launch_bounds__(256) void usym_kernel(
    const float* __restrict__ U3_0, const float* __restrict__ U2_0,
    const float* __restrict__ U3_1, const float* __restrict__ U2_1,
    float* __restrict__ ws_f) {
  int idx = blockIdx.x * 256 + threadIdx.x;
  if (idx < 4 * NT3 * 23) {
    int k = idx % 23;
    int t = (idx / 23) % NT3;
    int d4 = idx / (23 * NT3);
    int d = (d4 == 0) ? 0 : d4 - 1;
    const float* U3 = (d4 == 0) ? U3_0 : U3_1;
    int rem = t, p = 0;
    for (;;) { int tp = (9 - p) * (10 - p) / 2; if (rem < tp) break; rem -= tp; ++p; }
    int q = p;
    for (;;) { int ln = 9 - q; if (rem < ln) break; rem -= ln; ++q; }
    int i = q + rem;
    auto u3 = [&](int a, int b, int g) {
      return U3[(((d * 9 + a) * 9 + b) * 9 + g) * 23 + k];
    };
    float s;
    if (p == q && q == i)      s = u3(p, p, p);
    else if (p == q)           s = u3(p, p, i) + u3(p, i, p) + u3(i, p, p);
    else if (q == i)           s = u3(p, q, q) + u3(q, p, q) + u3(q, q, p);
    else                       s = u3(p, q, i) + u3(p, i, q) + u3(q, p, i)
                                 + u3(q, i, p) + u3(i, p, q) + u3(i, q, p);
    ws_f[O_U3S + (d4 * NT3 + t) * 23 + k] = s;
  } else {
    int idx2 = idx - 4 * NT3 * 23;
    if (idx2 >= 4 * NT2 * 8) return;
    int k = idx2 % 8;
    int j = (idx2 / 8) % NT2;
    int d4 = idx2 / (8 * NT2);
    int d = (d4 == 0) ? 0 : d4 - 1;
    const float* U2 = (d4 == 0) ? U2_0 : U2_1;
    int rem = j, p = 0;
    while (rem >= 9 - p) { rem -= 9 - p; ++p; }
    int q = p + rem;
    auto u2 = [&](int a, int b) { return U2[((d * 9 + a) * 9 + b) * 8 + k]; };
    ws_f[O_U2S + (d4 * NT2 + j) * 8 + k] = (p == q) ? u2(p, p) : u2(p, q) + u2(q, p);
  }
}

// ---------------- kernel 2 v4: emit packed folded V slabs --------------------
// grid (57, NSLAB), block 128 = channel c.
// sidx 0..41  -> V3S slots (4 terms each)
// sidx 42..53 -> V2S slots
// sidx 54..56 -> V1 slots
__global__ __launch_bounds__(128) void vpre4_kernel(
    const float* __restrict__ U1_0, const float* __restrict__ U1_1,
    const float* __restrict__ W3_0, const float* __restrict__ W2_0, const float* __restrict__ W1_0,
    const float* __restrict__ W3_1, const float* __restrict__ W2_1, const float* __restrict__ W1_1,
    float* __restrict__ ws_f) {
  int slab = blockIdx.y;
  int e = slab >> 2, dsel = slab & 3;
  int d = (dsel == 0) ? 0 : dsel - 1;
  const float* W3 = (dsel == 0) ? W3_0 : W3_1;
  const float* W2 = (dsel == 0) ? W2_0 : W2_1;
  const float* W1 = (dsel == 0) ? W1_0 : W1_1;
  const float* U1 = (dsel == 0) ? U1_0 : U1_1;
  int c = threadIdx.x;
  int sidx = blockIdx.x;
  float acc[4] = {0.f, 0.f, 0.f, 0.f};
  if (sidx < 42) {
    int t0 = 4 * sidx;
    const float* u = ws_f + O_U3S + dsel * NT3 * 23;
    for (int k = 0; k < 23; ++k) {
      float w = W3[(e * 23 + k) * C_ + c];
      #pragma unroll
      for (int l = 0; l < 4; ++l)
        if (t0 + l < NT3) acc[l] = fmaf(u[(t0 + l) * 23 + k], w, acc[l]);
    }
    ((float4*)(ws_f + O_B))[((size_t)slab * 42 + sidx) * C_ + c] =
        make_float4(acc[0], acc[1], acc[2], acc[3]);
  } else if (sidx < 54) {
    int j0 = 4 * (sidx - 42);
    const float* u = ws_f + O_U2S + dsel * NT2 * 8;
    for (int k = 0; k < 8; ++k) {
      float w = W2[(e * 8 + k) * C_ + c];
      #pragma unroll
      for (int l = 0; l < 4; ++l)
        if (j0 + l < NT2) acc[l] = fmaf(u[(j0 + l) * 8 + k], w, acc[l]);
    }
    ((float4*)(ws_f + O_A))[((size_t)slab * 12 + (sidx - 42)) * C_ + c] =
        make_float4(acc[0], acc[1], acc[2], acc[3]);
  } else {
    int p0 = 4 * (sidx - 54);
    for (int k = 0; k < 3; ++k) {
      float w = W1[(e * 3 + k) * C_ + c];
      #pragma unroll
      for (int l = 0; l < 4; ++l)
        if (p0 + l < 9) acc[l] = fmaf(U1[(d * 9 + p0 + l) * 3 + k], w, acc[l]);
    }
    ((float4*)(ws_f + O_C))[((size_t)slab * 3 + (sidx - 54)) * C_ + c] =
        make_float4(acc[0], acc[1], acc[2], acc[3]);
  }
}

// ---------------- kernel 3 v5: symmetric-folded contraction ------------------
// f = sum_{p<=q} x_p x_q (S2[pq] + sum_{i>=q} x_i S3[pqi]) + sum_p x_p V1[p]
// 256 thr: c = t&127, s-half splits pairs (p in {0,1} | p in {2..8}).
template<int P0, int P1, bool DOV1>
__device__ __forceinline__ void accum_sym(const float4* __restrict__ A4,
                                          const float4* __restrict__ B4,
                                          const float4* __restrict__ C4,
                                          const float (&xm)[M_][I_], float (&f)[M_]) {
  #pragma unroll
  for (int p = P0; p < P1; ++p) {
    #pragma unroll
    for (int q = p; q < 9; ++q) {
      const int j  = 45 - (9 - p) * (10 - p) / 2 + (q - p);
      const int tb = 165 - (9 - p) * (10 - p) * (11 - p) / 6
                   + (9 - p) * (10 - p) / 2 - (9 - q) * (10 - q) / 2 - q;
      float s2 = f4lane(A4[(j >> 2) * C_], j & 3);
      float tv[M_];
      #pragma unroll
      for (int m = 0; m < M_; ++m) tv[m] = s2;
      #pragma unroll
      for (int i = q; i < 9; ++i) {
        const int tt = tb + i;
        float v = f4lane(B4[(tt >> 2) * C_], tt & 3);
        #pragma unroll
        for (int m = 0; m < M_; ++m) tv[m] = fmaf(xm[m][i], v, tv[m]);
      }
      #pragma unroll
      for (int m = 0; m < M_; ++m) {
        float xx = xm[m][p] * xm[m][q];
        f[m] = fmaf(xx, tv[m], f[m]);
      }
    }
  }
  if (DOV1) {
    #pragma unroll
    for (int p = 0; p < 9; ++p) {
      float v = f4lane(C4[(p >> 2) * C_], p & 3);
      #pragma unroll
      for (int m = 0; m < M_; ++m) f[m] = fmaf(xm[m][p], v, f[m]);
    }
  }
}

__global__ __launch_bounds__(256) void contract5_kernel(
    const float* __restrict__ x, const float* __restrict__ ws_f,
    const int* __restrict__ order, const int* __restrict__ boff,
    float* __restrict__ fbuf) {
  int slab = (blockIdx.x & 7) + 8 * blockIdx.y;   // 0..39, pinned to XCD (x&7)
  int chunk = blockIdx.x >> 3;
  int e = slab >> 2, dsel = slab & 3;
  int b0 = boff[e];
  int cnt_e = boff[e + 1] - b0;
  int base = chunk * M_;
  if (base >= cnt_e) return;                      // block-uniform
  int cnt = cnt_e - base; if (cnt > M_) cnt = M_;
  int t = threadIdx.x;
  int c = t & 127, s = t >> 7;

  const float4* A4 = (const float4*)(ws_f + O_A) + (size_t)slab * 12 * C_ + c;
  const float4* B4 = (const float4*)(ws_f + O_B) + (size_t)slab * 42 * C_ + c;
  const float4* C4 = (const float4*)(ws_f + O_C) + (size_t)slab * 3 * C_ + c;

  int nn[M_];
  #pragma unroll
  for (int m = 0; m < M_; ++m) {
    int idx = base + m; if (idx >= cnt_e) idx = cnt_e - 1;
    nn[m] = order[b0 + idx];
  }
  float xm[M_][I_];
  #pragma unroll
  for (int m = 0; m < M_; ++m) {
    const float* xp = x + (nn[m] * C_ + c) * I_;
    #pragma unroll
    for (int i = 0; i < I_; ++i) xm[m][i] = xp[i];
  }
  float f[M_];
  #pragma unroll
  for (int m = 0; m < M_; ++m) f[m] = 0.f;

  __shared__ float red[C_][M_ + 1];

  if (s == 0) {
    accum_sym<0, 2, true>(A4, B4, C4, xm, f);     // pairs p=0,1 (81 terms) + V1
  } else {
    accum_sym<2, 9, false>(A4, B4, C4, xm, f);    // pairs p=2..8 (84 terms)
    #pragma unroll
    for (int m = 0; m < M_; ++m) red[c][m] = f[m];
  }
  __syncthreads();
  if (s == 0) {
    #pragma unroll
    for (int m = 0; m < M_; ++m) f[m] += red[c][m];
    #pragma unroll
    for (int m = 0; m < M_; ++m)
      if (m < cnt) fbuf[(nn[m] * 4 + dsel) * C_ + c] = f[m];
  }
}

// ---------------- kernel 4: equivariant linear + skip, dt-split --------------
__global__ __launch_bounds__(128) void linear3_kernel(
    const float* __restrict__ fbuf, const float* __restrict__ Wlin0,
    const float* __restrict__ Wlin1, const float* __restrict__ sc,
    float* __restrict__ out) {
  constexpr int NB = 8;
  int dt = blockIdx.y;
  int nb = blockIdx.x * NB;
  int w = threadIdx.x;
  __shared__ float fs[NB][C_];
  constexpr float inv = 0.08838834764831843f;  // 1/sqrt(128)
  #pragma unroll
  for (int r = 0; r < NB; ++r) fs[r][w] = fbuf[((nb + r) * 4 + dt) * C_ + w];
  __syncthreads();
  const float* Wl = (dt == 0) ? Wlin0 : Wlin1;
  float acc[NB];
  #pragma unroll
  for (int r = 0; r < NB; ++r) acc[r] = 0.f;
  for (int u = 0; u < C_; ++u) {
    float wv = Wl[u * C_ + w];
    #pragma unroll
    for (int r = 0; r < NB; ++r) acc[r] = fmaf(fs[r][u], wv, acc[r]);
  }
  if (dt == 0) {
    #pragma unroll
    for (int r = 0; r < NB; ++r) { int o = (nb + r) * 512 + w; out[o] = acc[r] * inv + sc[o]; }
  } else {
    int col = 128 + w * 3 + (dt - 1);
    #pragma unroll
    for (int r = 0; r < NB; ++r) { int o = (nb + r) * 512 + col; out[o] = acc[r] * inv + sc[o]; }
  }
}

// ---------------- launcher ---------------------------------------------------
extern "C" void kernel_launch(void* const* d_in, const int* in_sizes, int n_in,
                              void* d_out, int out_size, void* d_ws, size_t ws_size,
                              hipStream_t stream) {
  const float* node_feats = (const float*)d_in[0];
  const float* sc         = (const float*)d_in[1];
  const float* node_attrs = (const float*)d_in[2];
  const float* U3_0 = (const float*)d_in[3];
  const float* U2_0 = (const float*)d_in[4];
  const float* U1_0 = (const float*)d_in[5];
  const float* W3_0 = (const float*)d_in[6];
  const float* W2_0 = (const float*)d_in[7];
  const float* W1_0 = (const float*)d_in[8];
  const float* U3_1 = (const float*)d_in[9];
  const float* U2_1 = (const float*)d_in[10];
  const float* U1_1 = (const float*)d_in[11];
  const float* W3_1 = (const float*)d_in[12];
  const float* W2_1 = (const float*)d_in[13];
  const float* W1_1 = (const float*)d_in[14];
  const float* Wlin0 = (const float*)d_in[15];
  const float* Wlin1 = (const float*)d_in[16];

  float* ws_f = (float*)d_ws;
  int*   ws_i = (int*)d_ws;

  bucket_kernel<<<1, 1024, 0, stream>>>(node_attrs, ws_i + O_ORDER, ws_i + O_BOFF);

  usym_kernel<<<(4 * NT3 * 23 + 4 * NT2 * 8 + 255) / 256, 256, 0, stream>>>(
      U3_0, U2_0, U3_1, U2_1, ws_f);

  vpre4_kernel<<<dim3(57, NSLAB), 128, 0, stream>>>(
      U1_0, U1_1, W3_0, W2_0, W1_0, W3_1, W2_1, W1_1, ws_f);

  contract5_kernel<<<dim3(NCHUNK * 8, 5), 256, 0, stream>>>(
      node_feats, ws_f, ws_i + O_ORDER, ws_i + O_BOFF, ws_f + O_F);

  linear3_kernel<<<dim3(N_ / 8, 4), 128, 0, stream>>>(ws_f + O_F, Wlin0, Wlin1, sc, (float*)d_out);
}